// Round 8
// baseline (596.865 us; speedup 1.0000x reference)
//
#include <hip/hip_runtime.h>

// MOE transformer block — bf16 MFMA, v2: pre-transposed bf16 weights.
// conv(W fp32[K][N] -> WT bf16[N][K]) once per launch; all GEMMs then use
// global_load_lds for BOTH operands (m97 structure).
// LN1->QKV(V^T out)->flash attn->O-proj(+resid)->LN2->FFN1(silu)->FFN2(+resid).

typedef unsigned int  u32;
typedef unsigned short u16;
typedef short v8s __attribute__((ext_vector_type(8)));   // 8 x bf16 fragment
typedef float v4f __attribute__((ext_vector_type(4)));   // 4 x f32 accum

#define SEQ  2048
#define DIM_ 1024
#define EPS_ 1e-5f

__device__ __forceinline__ u16 f2bf(float f) {
    __bf16 h = (__bf16)f;
    return __builtin_bit_cast(u16, h);
}

__device__ __forceinline__ void gload16(const void* g, void* l) {
    __builtin_amdgcn_global_load_lds((const __attribute__((address_space(1))) u32*)g,
                                     (__attribute__((address_space(3))) u32*)l, 16, 0, 0);
}

// ------------------------------------------------- weight transpose+cast
// src fp32 [K][N] (matrix z of 4 sep ptrs, or z-th slab of s0) -> dst bf16 [N][K].
template<bool SEP>
__global__ __launch_bounds__(256) void conv_t(const float* __restrict__ s0,
                                              const float* __restrict__ s1,
                                              const float* __restrict__ s2,
                                              const float* __restrict__ s3,
                                              u16* __restrict__ dst, int K, int N) {
    __shared__ __attribute__((aligned(16))) u16 Ts[64][72];   // 144B rows
    int tid = threadIdx.x;
    int z = blockIdx.z;
    const float* src = SEP ? (z == 0 ? s0 : z == 1 ? s1 : z == 2 ? s2 : s3)
                           : s0 + (size_t)z * K * N;
    u16* d = dst + (size_t)z * K * N;
    int k0 = blockIdx.y * 64, n0 = blockIdx.x * 64;
    int tk = tid >> 4, tn = tid & 15;

    u16 t[4][4];
    #pragma unroll
    for (int r = 0; r < 4; r++) {
        float4 L = *(const float4*)&src[(size_t)(k0 + tk * 4 + r) * N + n0 + tn * 4];
        t[r][0] = f2bf(L.x); t[r][1] = f2bf(L.y); t[r][2] = f2bf(L.z); t[r][3] = f2bf(L.w);
    }
    #pragma unroll
    for (int c = 0; c < 4; c++) {
        ushort4 q4 = { t[0][c], t[1][c], t[2][c], t[3][c] };
        *(ushort4*)&Ts[tn * 4 + c][tk * 4] = q4;
    }
    __syncthreads();
    #pragma unroll
    for (int i = 0; i < 2; i++) {
        int id = tid + i * 256;
        int row = id >> 3, ch = id & 7;
        v8s val = *(const v8s*)&Ts[row][ch * 8];
        *(v8s*)&d[(size_t)(n0 + row) * K + k0 + ch * 8] = val;
    }
}

// ---------------------------------------------------------------- LayerNorm (fp32 in, bf16 out)
__global__ __launch_bounds__(256) void ln_kernel(const float* __restrict__ x,
                                                 const float* __restrict__ g,
                                                 const float* __restrict__ b,
                                                 u16* __restrict__ out) {
    int row = blockIdx.x;
    int t = threadIdx.x;
    const float4* xr = (const float4*)(x + (size_t)row * DIM_);
    float4 v = xr[t];
    float s  = v.x + v.y + v.z + v.w;
    float ss = v.x*v.x + v.y*v.y + v.z*v.z + v.w*v.w;
    #pragma unroll
    for (int off = 32; off > 0; off >>= 1) {
        s  += __shfl_down(s, off);
        ss += __shfl_down(ss, off);
    }
    __shared__ float red[8];
    if ((t & 63) == 0) { red[t >> 6] = s; red[4 + (t >> 6)] = ss; }
    __syncthreads();
    s  = red[0] + red[1] + red[2] + red[3];
    ss = red[4] + red[5] + red[6] + red[7];
    float mean = s * (1.0f / DIM_);
    float var  = ss * (1.0f / DIM_) - mean * mean;
    float rstd = rsqrtf(var + EPS_);
    float4 gv = ((const float4*)g)[t];
    float4 bv = ((const float4*)b)[t];
    ushort4 ov;
    ov.x = f2bf((v.x - mean) * rstd * gv.x + bv.x);
    ov.y = f2bf((v.y - mean) * rstd * gv.y + bv.y);
    ov.z = f2bf((v.z - mean) * rstd * gv.z + bv.z);
    ov.w = f2bf((v.w - mean) * rstd * gv.w + bv.w);
    *(ushort4*)(out + (size_t)row * DIM_ + t * 4) = ov;
}

// ---------------------------------------------------------------- bf16 MFMA GEMM
// C[M,N] = A[M,K](bf16) @ WT[N,K](bf16) + bias. Both operands via global_load_lds
// (linear LDS dest, inverse-swizzled source; XOR-swizzled ds_read_b128).
// WMODE 0: fp32 out + resid ; 1: bf16 out (+silu) ; 2: fused QKV (q,k bf16; v->V^T).
// GROUPED: blockIdx.y=(batch,expert,half); per-expert WT slab / bias.
template<int BN, int ACT, bool GROUPED, int WMODE>
__global__ __launch_bounds__(256) void gemm_bf16(
    const u16* __restrict__ A, const u16* __restrict__ WT,
    const float* __restrict__ b0, const float* __restrict__ bk2, const float* __restrict__ bv2,
    const float* __restrict__ resid, float* __restrict__ Cf,
    u16* __restrict__ Cb, u16* __restrict__ Ckb, u16* __restrict__ vtb,
    int Nw, int K)
{
    constexpr int BM = 128;
    constexpr int MI = 4;
    constexpr int NI = BN / 32;           // N-frags per wave; also B-stage instrs/wave
    __shared__ __attribute__((aligned(16))) char AsB[BM * 128];
    __shared__ __attribute__((aligned(16))) char BsB[BN * 128];

    int tid = threadIdx.x;
    int lane = tid & 63, w = tid >> 6;
    int wr = w >> 1, wc = w & 1;
    int g = lane >> 4, lq = lane & 15;

    long row0; int e = 0;
    const float* bias = b0;
    if (GROUPED) {
        int seg = blockIdx.y >> 1, mh = blockIdx.y & 1;
        int bb = seg >> 3; e = seg & 7;
        row0 = (long)bb * SEQ + e * 256 + mh * BM;
        bias += (size_t)e * Nw;
    } else row0 = (long)blockIdx.y * BM;

    int col0 = blockIdx.x * BN;           // global col (QKV: 0..3071)
    int colL = col0;
    if (WMODE == 2) {
        int sel = col0 >> 10; colL = col0 & 1023;
        if (sel == 1)      bias = bk2;
        else if (sel == 2) bias = bv2;
    }

    const u16* Arow = A + (size_t)row0 * K;
    const u16* Brow = WT + (GROUPED ? ((size_t)e * Nw + col0) : (size_t)col0) * K;

    v4f acc[MI][NI];
    #pragma unroll
    for (int mi = 0; mi < MI; mi++)
        #pragma unroll
        for (int ni = 0; ni < NI; ni++) acc[mi][ni] = (v4f){0.f, 0.f, 0.f, 0.f};

    for (int kt = 0; kt < K; kt += 64) {
        #pragma unroll
        for (int i = 0; i < 4; i++) {                 // A tile: 128 rows
            int R0 = (i * 4 + w) * 8;
            int row = R0 + (lane >> 3);
            gload16(Arow + (size_t)row * K + kt + (((lane & 7) ^ (row & 7)) << 3),
                    AsB + R0 * 128);
        }
        #pragma unroll
        for (int i = 0; i < NI; i++) {                // B tile: BN rows
            int R0 = (i * 4 + w) * 8;
            int row = R0 + (lane >> 3);
            gload16(Brow + (size_t)row * K + kt + (((lane & 7) ^ (row & 7)) << 3),
                    BsB + R0 * 128);
        }
        __syncthreads();
        #pragma unroll
        for (int kk = 0; kk < 64; kk += 32) {
            v8s af[MI], bfv[NI];
            int slot = (kk >> 3) + g;
            #pragma unroll
            for (int mi = 0; mi < MI; mi++) {
                int row = wr * 64 + mi * 16 + lq;
                af[mi] = *(const v8s*)(AsB + row * 128 + ((slot ^ (row & 7)) << 4));
            }
            #pragma unroll
            for (int ni = 0; ni < NI; ni++) {
                int rn = wc * (BN / 2) + ni * 16 + lq;
                bfv[ni] = *(const v8s*)(BsB + rn * 128 + ((slot ^ (rn & 7)) << 4));
            }
            #pragma unroll
            for (int mi = 0; mi < MI; mi++)
                #pragma unroll
                for (int ni = 0; ni < NI; ni++)
                    acc[mi][ni] = __builtin_amdgcn_mfma_f32_16x16x32_bf16(
                        af[mi], bfv[ni], acc[mi][ni], 0, 0, 0);
        }
        __syncthreads();
    }

    // epilogue. D frag: row=(lane>>4)*4+r, col=lane&15
    #pragma unroll
    for (int mi = 0; mi < MI; mi++) {
        int grow = wr * 64 + mi * 16 + g * 4;
        #pragma unroll
        for (int ni = 0; ni < NI; ni++) {
            int cL = colL + wc * (BN / 2) + ni * 16 + lq;
            float bb_ = bias[cL];
            v4f a = acc[mi][ni];
            if (WMODE == 0) {
                #pragma unroll
                for (int r = 0; r < 4; r++) {
                    float val = a[r] + bb_;
                    if (ACT == 1) val = val / (1.0f + __expf(-val));
                    size_t idx = (size_t)(row0 + grow + r) * Nw + cL;
                    val += resid[idx];
                    Cf[idx] = val;
                }
            } else if (WMODE == 1) {
                #pragma unroll
                for (int r = 0; r < 4; r++) {
                    float val = a[r] + bb_;
                    if (ACT == 1) val = val / (1.0f + __expf(-val));
                    Cb[(size_t)(row0 + grow + r) * Nw + cL] = f2bf(val);
                }
            } else {
                int sel = col0 >> 10;
                if (sel < 2) {
                    u16* dst = (sel == 0) ? Cb : Ckb;
                    #pragma unroll
                    for (int r = 0; r < 4; r++)
                        dst[(size_t)(row0 + grow + r) * 1024 + cL] = f2bf(a[r] + bb_);
                } else {
                    long token0 = row0 + grow;
                    int bb2 = (int)(token0 >> 11);
                    int ss  = (int)(token0 & 2047);
                    int hh = cL >> 6, dd = cL & 63;
                    ushort4 pv_;
                    pv_.x = f2bf(a[0] + bb_); pv_.y = f2bf(a[1] + bb_);
                    pv_.z = f2bf(a[2] + bb_); pv_.w = f2bf(a[3] + bb_);
                    *(ushort4*)(vtb + ((size_t)(bb2 * 16 + hh) * 64 + dd) * 2048 + ss) = pv_;
                }
            }
        }
    }
}

// ---------------------------------------------------------------- MFMA flash attention
// grid (16 qtiles, 16 heads, 2 batch), 4 waves, 32 q-rows/wave. Swapped QK^T,
// defer-max (T13), P via per-wave padded LDS. fp32 softmax/accum.
__global__ __launch_bounds__(256) void attn_kernel(const u16* __restrict__ qb,
                                                   const u16* __restrict__ kb,
                                                   const u16* __restrict__ vtb,
                                                   u16* __restrict__ ob) {
    __shared__ __attribute__((aligned(16))) char Kl[8192];
    __shared__ __attribute__((aligned(16))) char Vl[8192];
    __shared__ __attribute__((aligned(16))) char Pl[4][4608];

    int tid = threadIdx.x;
    int lane = tid & 63, w = tid >> 6;
    int g = lane >> 4, lq = lane & 15;
    int h = blockIdx.y, bz = blockIdx.z;
    int q0 = blockIdx.x * 128 + w * 32;
    const size_t hb = (size_t)h * 64;

    v8s qfr[2][2];
    #pragma unroll
    for (int qi = 0; qi < 2; qi++)
        #pragma unroll
        for (int kkh = 0; kkh < 2; kkh++)
            qfr[qi][kkh] = *(const v8s*)(qb + ((size_t)(bz * SEQ + q0 + qi * 16 + lq)) * DIM_
                                         + hb + kkh * 32 + g * 8);

    v4f oacc[2][4];
    #pragma unroll
    for (int qi = 0; qi < 2; qi++)
        #pragma unroll
        for (int df = 0; df < 4; df++) oacc[qi][df] = (v4f){0.f, 0.f, 0.f, 0.f};
    float m_prev[2] = {-1e30f, -1e30f}, l_acc[2] = {0.f, 0.f};

    for (int kv = 0; kv < SEQ; kv += 64) {
        __syncthreads();
        #pragma unroll
        for (int i = 0; i < 2; i++) {
            int beta = (i * 4 + w) * 1024 + lane * 16;
            int row  = beta >> 7;
            int sc   = ((lane & 7) ^ (row & 7)) << 3;
            gload16(kb + ((size_t)(bz * SEQ + kv + row)) * DIM_ + hb + sc,
                    Kl + (i * 4 + w) * 1024);
            gload16(vtb + ((size_t)((bz * 16 + h) * 64 + row)) * 2048 + kv + sc,
                    Vl + (i * 4 + w) * 1024);
        }
        __syncthreads();

        v4f sa[4][2];
        #pragma unroll
        for (int cf = 0; cf < 4; cf++)
            #pragma unroll
            for (int qi = 0; qi < 2; qi++) sa[cf][qi] = (v4f){0.f, 0.f, 0.f, 0.f};
        #pragma unroll
        for (int kkh = 0; kkh < 2; kkh++) {
            v8s kf[4];
            int slot = kkh * 4 + g;
            #pragma unroll
            for (int cf = 0; cf < 4; cf++) {
                int row = cf * 16 + lq;
                kf[cf] = *(const v8s*)(Kl + row * 128 + ((slot ^ (row & 7)) << 4));
            }
            #pragma unroll
            for (int cf = 0; cf < 4; cf++)
                #pragma unroll
                for (int qi = 0; qi < 2; qi++)
                    sa[cf][qi] = __builtin_amdgcn_mfma_f32_16x16x32_bf16(
                        kf[cf], qfr[qi][kkh], sa[cf][qi], 0, 0, 0);
        }

        #pragma unroll
        for (int qi = 0; qi < 2; qi++) {
            float mx = -1e30f;
            #pragma unroll
            for (int cf = 0; cf < 4; cf++)
                #pragma unroll
                for (int r = 0; r < 4; r++) mx = fmaxf(mx, sa[cf][qi][r]);
            mx = fmaxf(mx, __shfl_xor(mx, 16));
            mx = fmaxf(mx, __shfl_xor(mx, 32));
            float rm = mx * 0.125f;
            if (__any(rm - m_prev[qi] > 8.0f)) {
                float mnew = fmaxf(m_prev[qi], rm);
                float corr = __expf(m_prev[qi] - mnew);
                m_prev[qi] = mnew;
                l_acc[qi] *= corr;
                #pragma unroll
                for (int r = 0; r < 4; r++) {
                    float cr = __shfl(corr, (lane & 48) | (g * 4 + r));
                    #pragma unroll
                    for (int df = 0; df < 4; df++) oacc[qi][df][r] *= cr;
                }
            }
            float rs = 0.f;
            float ps[4][4];
            #pragma unroll
            for (int cf = 0; cf < 4; cf++)
                #pragma unroll
                for (int r = 0; r < 4; r++) {
                    float p = __expf(sa[cf][qi][r] * 0.125f - m_prev[qi]);
                    ps[cf][r] = p; rs += p;
                }
            rs += __shfl_xor(rs, 16);
            rs += __shfl_xor(rs, 32);
            l_acc[qi] += rs;
            #pragma unroll
            for (int cf = 0; cf < 4; cf++) {
                ushort4 pw;
                pw.x = f2bf(ps[cf][0]); pw.y = f2bf(ps[cf][1]);
                pw.z = f2bf(ps[cf][2]); pw.w = f2bf(ps[cf][3]);
                *(ushort4*)(Pl[w] + (qi * 16 + lq) * 144 + (cf * 16 + g * 4) * 2) = pw;
            }
        }
        asm volatile("s_waitcnt lgkmcnt(0)" ::: "memory");
        __builtin_amdgcn_sched_barrier(0);

        #pragma unroll
        for (int kkh = 0; kkh < 2; kkh++) {
            v8s pa[2], vf[4];
            int slot = kkh * 4 + g;
            #pragma unroll
            for (int qi = 0; qi < 2; qi++)
                pa[qi] = *(const v8s*)(Pl[w] + (qi * 16 + lq) * 144 + kkh * 64 + g * 16);
            #pragma unroll
            for (int df = 0; df < 4; df++) {
                int row = df * 16 + lq;
                vf[df] = *(const v8s*)(Vl + row * 128 + ((slot ^ (row & 7)) << 4));
            }
            #pragma unroll
            for (int qi = 0; qi < 2; qi++)
                #pragma unroll
                for (int df = 0; df < 4; df++)
                    oacc[qi][df] = __builtin_amdgcn_mfma_f32_16x16x32_bf16(
                        pa[qi], vf[df], oacc[qi][df], 0, 0, 0);
        }
    }

    #pragma unroll
    for (int qi = 0; qi < 2; qi++) {
        float inv = 1.0f / l_acc[qi];
        #pragma unroll
        for (int r = 0; r < 4; r++) {
            float ivr = __shfl(inv, (lane & 48) | (g * 4 + r));
            size_t rowi = (size_t)(bz * SEQ + q0 + qi * 16 + g * 4 + r) * DIM_ + hb;
            #pragma unroll
            for (int df = 0; df < 4; df++)
                ob[rowi + df * 16 + lq] = f2bf(oacc[qi][df][r] * ivr);
        }
    }
}

// ---------------------------------------------------------------- launcher
extern "C" void kernel_launch(void* const* d_in, const int* in_sizes, int n_in,
                              void* d_out, int out_size, void* d_ws, size_t ws_size,
                              hipStream_t stream) {
    const float* x     = (const float*)d_in[0];
    const float* ln1_g = (const float*)d_in[1];
    const float* ln1_b = (const float*)d_in[2];
    const float* ln2_g = (const float*)d_in[3];
    const float* ln2_b = (const float*)d_in[4];
    const float* wq = (const float*)d_in[5];  const float* bq = (const float*)d_in[6];
    const float* wk = (const float*)d_in[7];  const float* bk = (const float*)d_in[8];
    const float* wv = (const float*)d_in[9];  const float* bv = (const float*)d_in[10];
    const float* wo = (const float*)d_in[11]; const float* bo = (const float*)d_in[12];
    const float* w1 = (const float*)d_in[13]; const float* b1 = (const float*)d_in[14];
    const float* w2 = (const float*)d_in[15]; const float* b2 = (const float*)d_in[16];

    char* wsb = (char*)d_ws;
    const size_t MB = 1024 * 1024;
    // lifetimes: wqkvoT dead after o-proj (before mid written); w1T dead after
    // FFN1 -> w2T aliases it. Total footprint = 144 MB (= round-1 proven size).
    u16*   h1   = (u16*)(wsb + 0 * MB);     // 8 MB  [4096][1024] bf16; ob after attn
    u16*   qbf  = (u16*)(wsb + 8 * MB);     // 8 MB ; h2 after attn
    u16*   kbf  = (u16*)(wsb + 16 * MB);    // 8 MB
    u16*   vt   = (u16*)(wsb + 24 * MB);    // 8 MB  V^T [2][16][64][2048]
    float* x2   = (float*)(wsb + 32 * MB);  // 16 MB fp32
    u16*   wqkvoT = (u16*)(wsb + 48 * MB);  // 8 MB  [4][1024][1024] (q,k,v,o)
    u16*   mid  = (u16*)(wsb + 48 * MB);    // 32 MB [4096][4096] bf16 (after o-proj)
    u16*   w1T  = (u16*)(wsb + 80 * MB);    // 64 MB [8][4096][1024]
    u16*   w2T  = (u16*)(wsb + 80 * MB);    // 64 MB [8][1024][4096] (after FFN1)
    u16*   ob   = h1;
    u16*   h2   = qbf;
    float* outp = (float*)d_out;

    conv_t<true ><<<dim3(16, 16, 4), 256, 0, stream>>>(wq, wk, wv, wo, wqkvoT, 1024, 1024);
    conv_t<false><<<dim3(64, 16, 8), 256, 0, stream>>>(w1, nullptr, nullptr, nullptr, w1T, 1024, 4096);

    ln_kernel<<<4096, 256, 0, stream>>>(x, ln1_g, ln1_b, h1);

    gemm_bf16<128, 0, false, 2><<<dim3(24, 32), 256, 0, stream>>>(
        h1, wqkvoT, bq, bk, bv, nullptr, nullptr, qbf, kbf, vt, 1024, 1024);

    attn_kernel<<<dim3(16, 16, 2), 256, 0, stream>>>(qbf, kbf, vt, ob);

    gemm_bf16<64, 0, false, 0><<<dim3(16, 32), 256, 0, stream>>>(
        ob, wqkvoT + (size_t)3 * 1024 * 1024, bo, nullptr, nullptr, x, x2,
        nullptr, nullptr, nullptr, 1024, 1024);

    ln_kernel<<<4096, 256, 0, stream>>>(x2, ln2_g, ln2_b, h2);

    gemm_bf16<128, 1, true, 1><<<dim3(32, 32), 256, 0, stream>>>(
        h2, w1T, b1, nullptr, nullptr, nullptr, nullptr,
        mid, nullptr, nullptr, 4096, 1024);

    conv_t<false><<<dim3(16, 64, 8), 256, 0, stream>>>(w2, nullptr, nullptr, nullptr, w2T, 4096, 1024);

    gemm_bf16<64, 0, true, 0><<<dim3(16, 32), 256, 0, stream>>>(
        mid, w2T, b2, nullptr, nullptr, x2, outp,
        nullptr, nullptr, nullptr, 1024, 4096);
}